// Round 1
// baseline (135.059 us; speedup 1.0000x reference)
//
#include <hip/hip_runtime.h>

// GraphConv on MI355X.
// Factorization: edge MLP layer1 relu(ns[s]@W1t + ns[r]@W1b + b1) -> per-node
// partials P,Q precomputed; layer2 (64x64) done with bf16 MFMA per (b, recv-tile).
// Decoder fused into main kernel.

typedef __attribute__((ext_vector_type(8))) short bh8;   // 8 x bf16 (bit pattern)
typedef __attribute__((ext_vector_type(4))) float fv4;   // MFMA accumulator

static __device__ __forceinline__ unsigned short f2bf(float f) {
  union { float f; unsigned u; } v; v.f = f;
  unsigned r = v.u + 0x7fffu + ((v.u >> 16) & 1u);   // RNE truncate to bf16
  return (unsigned short)(r >> 16);
}

// ---------------- prep kernel ----------------
// blocks 0..2047  : P0/Q0/P1/Q1[b,n,h] (Q includes +b1)
// blocks 2048..2083: W2 transposed -> bf16, padded rows of 72 (2 encoders)
__global__ __launch_bounds__(256) void prep_kernel(
    const float* __restrict__ ns,
    const float* __restrict__ e0w1, const float* __restrict__ e0b1,
    const float* __restrict__ e1w1, const float* __restrict__ e1b1,
    const float* __restrict__ e0w2, const float* __restrict__ e1w2,
    float* __restrict__ P0, float* __restrict__ Q0,
    float* __restrict__ P1, float* __restrict__ Q1,
    unsigned short* __restrict__ W2T)
{
  int bid = blockIdx.x, t = threadIdx.x;
  if (bid < 2048) {
    __shared__ float nsl[64];
    int b = bid >> 4, ng = bid & 15;
    if (t < 64) nsl[t] = ns[(b*64 + ng*4)*16 + t];
    __syncthreads();
    int n = ng*4 + (t >> 6), h = t & 63, li = (t >> 6)*16;
    float p0 = 0.f, q0 = 0.f, p1 = 0.f, q1 = 0.f;
#pragma unroll
    for (int k = 0; k < 16; ++k) {
      float x = nsl[li + k];
      p0 += x * e0w1[k*64 + h];
      q0 += x * e0w1[(16 + k)*64 + h];
      p1 += x * e1w1[k*64 + h];
      q1 += x * e1w1[(16 + k)*64 + h];
    }
    int row = b*64 + n;
    P0[row*64 + h] = p0;
    Q0[row*64 + h] = q0 + e0b1[h];
    P1[row*64 + h] = p1;
    Q1[row*64 + h] = q1 + e1b1[h];
  } else {
    int idx = (bid - 2048)*256 + t;          // 0..9215
    int enc = idx / 4608, rem = idx % 4608;
    int n = rem / 72, kp = rem % 72;
    const float* w2 = enc ? e1w2 : e0w2;
    W2T[idx] = (kp < 64) ? f2bf(w2[kp*64 + n]) : (unsigned short)0;
  }
}

// ---------------- main kernel ----------------
// grid = 128 b * 8 recv-groups. Each block: 8 receivers, all 64 senders.
__global__ __launch_bounds__(256) void main_kernel(
    const float* __restrict__ ns, const float* __restrict__ et,
    const float* __restrict__ P0g, const float* __restrict__ Q0g,
    const float* __restrict__ P1g, const float* __restrict__ Q1g,
    const unsigned short* __restrict__ W2TW,
    const float* __restrict__ e0b2, const float* __restrict__ e1b2,
    const float* __restrict__ ndw1, const float* __restrict__ ndb1,
    const float* __restrict__ ndw2, const float* __restrict__ ndb2,
    float* __restrict__ out)
{
  __shared__ float Pl[2*64*68];          // 34816 B, aliased as HD in decoder
  __shared__ unsigned short W2T[2*64*72];// 18432 B
  __shared__ float Qb[2*8*64];           // 4096 B (Q + b1)
  __shared__ float ETl[2*8*64];          // 4096 B
  __shared__ float B2l[128];             // 512 B
  __shared__ float MSG[8*64];            // 2048 B
  __shared__ float NSR[8*16];            // 512 B

  int t = threadIdx.x;
  int b = blockIdx.x >> 3, rg = blockIdx.x & 7, r0 = rg*8;

  // ---- stage P (stride-68 pad) ----
  {
    const float4* src0 = (const float4*)(P0g + b*64*64);
    const float4* src1 = (const float4*)(P1g + b*64*64);
#pragma unroll
    for (int i = 0; i < 8; ++i) {
      int idx = t + i*256;               // 0..2047 float4s
      int enc = idx >> 10, rem = idx & 1023;
      int s = rem >> 4, c4 = rem & 15;
      float4 v = enc ? src1[rem] : src0[rem];
      *(float4*)(Pl + enc*4352 + s*68 + c4*4) = v;
    }
  }
  // ---- stage W2T (already bf16 + padded in ws) ----
  {
    const unsigned* src = (const unsigned*)W2TW;
    unsigned* dst = (unsigned*)W2T;
#pragma unroll
    for (int i = 0; i < 18; ++i) dst[t + i*256] = src[t + i*256];
  }
  // ---- stage Q+b1 ----
#pragma unroll
  for (int i = 0; i < 4; ++i) {
    int idx = t + i*256;                 // 0..1023
    int enc = idx >> 9, rem = idx & 511;
    int rl = rem >> 6, k = rem & 63;
    const float* Q = enc ? Q1g : Q0g;
    Qb[idx] = Q[(b*64 + r0 + rl)*64 + k];
  }
  // ---- gather edge-type weights: ET[enc][rl][s] ----
#pragma unroll
  for (int i = 0; i < 4; ++i) {
    int idx = t + i*256;
    int enc = idx >> 9, rem = idx & 511;
    int rl = rem >> 6, s = rem & 63;
    int r = r0 + rl;
    float v = 0.f;
    if (s != r) {
      int e = s*63 + (r < s ? r : r - 1);
      v = et[(b*4032 + e)*3 + 1 + enc];
    }
    ETl[idx] = v;
  }
  if (t < 128) B2l[t] = (t >= 64) ? e1b2[t - 64] : e0b2[t];
  if (t < 128) { int rl = t >> 4; NSR[t] = ns[(b*64 + r0 + rl)*16 + (t & 15)]; }
  __syncthreads();

  int w = t >> 6, lane = t & 63, quad = lane >> 4, col = lane & 15;
  float msgacc[2][4] = {{0.f,0.f,0.f,0.f},{0.f,0.f,0.f,0.f}};

#pragma unroll
  for (int enc = 0; enc < 2; ++enc) {
    // B fragments: W2[k][n], lane holds B[k=quad*8+j][n=col] per (nt,kk)
    bh8 bf[4][2];
    float b2v[4];
#pragma unroll
    for (int nt = 0; nt < 4; ++nt) {
#pragma unroll
      for (int kk = 0; kk < 2; ++kk)
        bf[nt][kk] = *(const bh8*)(W2T + enc*4608 + (nt*16 + col)*72 + kk*32 + quad*8);
      b2v[nt] = B2l[enc*64 + nt*16 + col];
    }
#pragma unroll
    for (int rli = 0; rli < 2; ++rli) {
      int rl = w*2 + rli;                 // this wave owns receivers 2w, 2w+1
      const float* qrow = Qb + (enc*8 + rl)*64;
      float4 qa0 = *(const float4*)(qrow + quad*8);
      float4 qa1 = *(const float4*)(qrow + quad*8 + 4);
      float4 qb0 = *(const float4*)(qrow + 32 + quad*8);
      float4 qb1 = *(const float4*)(qrow + 32 + quad*8 + 4);
      const float* etrow = ETl + (enc*8 + rl)*64;
#pragma unroll
      for (int st = 0; st < 4; ++st) {
        const float* prow = Pl + enc*4352 + (st*16 + col)*68;
        float4 pa0 = *(const float4*)(prow + quad*8);
        float4 pa1 = *(const float4*)(prow + quad*8 + 4);
        float4 pb0 = *(const float4*)(prow + 32 + quad*8);
        float4 pb1 = *(const float4*)(prow + 32 + quad*8 + 4);
        // h1 = relu(P[s] + Q[r] + b1) -> bf16 A-fragments (kk=0,1)
        bh8 a0, a1;
        a0[0] = (short)f2bf(fmaxf(pa0.x + qa0.x, 0.f));
        a0[1] = (short)f2bf(fmaxf(pa0.y + qa0.y, 0.f));
        a0[2] = (short)f2bf(fmaxf(pa0.z + qa0.z, 0.f));
        a0[3] = (short)f2bf(fmaxf(pa0.w + qa0.w, 0.f));
        a0[4] = (short)f2bf(fmaxf(pa1.x + qa1.x, 0.f));
        a0[5] = (short)f2bf(fmaxf(pa1.y + qa1.y, 0.f));
        a0[6] = (short)f2bf(fmaxf(pa1.z + qa1.z, 0.f));
        a0[7] = (short)f2bf(fmaxf(pa1.w + qa1.w, 0.f));
        a1[0] = (short)f2bf(fmaxf(pb0.x + qb0.x, 0.f));
        a1[1] = (short)f2bf(fmaxf(pb0.y + qb0.y, 0.f));
        a1[2] = (short)f2bf(fmaxf(pb0.z + qb0.z, 0.f));
        a1[3] = (short)f2bf(fmaxf(pb0.w + qb0.w, 0.f));
        a1[4] = (short)f2bf(fmaxf(pb1.x + qb1.x, 0.f));
        a1[5] = (short)f2bf(fmaxf(pb1.y + qb1.y, 0.f));
        a1[6] = (short)f2bf(fmaxf(pb1.z + qb1.z, 0.f));
        a1[7] = (short)f2bf(fmaxf(pb1.w + qb1.w, 0.f));
        float4 etv = *(const float4*)(etrow + st*16 + quad*4);
#pragma unroll
        for (int nt = 0; nt < 4; ++nt) {
          fv4 acc = {0.f, 0.f, 0.f, 0.f};
          acc = __builtin_amdgcn_mfma_f32_16x16x32_bf16(a0, bf[nt][0], acc, 0, 0, 0);
          acc = __builtin_amdgcn_mfma_f32_16x16x32_bf16(a1, bf[nt][1], acc, 0, 0, 0);
          // C layout: row(sender) = quad*4+reg, col(h) = col
          float m = msgacc[rli][nt];
          m += etv.x * fmaxf(acc[0] + b2v[nt], 0.f);
          m += etv.y * fmaxf(acc[1] + b2v[nt], 0.f);
          m += etv.z * fmaxf(acc[2] + b2v[nt], 0.f);
          m += etv.w * fmaxf(acc[3] + b2v[nt], 0.f);
          msgacc[rli][nt] = m;
        }
      }
    }
  }
  // quad reduction -> MSG[rl][h]
#pragma unroll
  for (int rli = 0; rli < 2; ++rli) {
#pragma unroll
    for (int nt = 0; nt < 4; ++nt) {
      float v = msgacc[rli][nt];
      v += __shfl_xor(v, 16);
      v += __shfl_xor(v, 32);
      if (lane < 16) MSG[(w*2 + rli)*64 + nt*16 + lane] = v;
    }
  }
  __syncthreads();

  // ---- decoder: relu(relu([ns, msg]@W1+b1)@W2+b2), fp32 ----
  float* HD = Pl;   // alias dead P region
#pragma unroll
  for (int pass = 0; pass < 2; ++pass) {
    int idx = pass*256 + t;              // 0..511 -> (rl, j)
    int rl = idx >> 6, j = idx & 63;
    float acc = ndb1[j];
    const float* x0 = NSR + rl*16;
#pragma unroll
    for (int i = 0; i < 16; ++i) acc += x0[i] * ndw1[i*64 + j];
    const float* mrow = MSG + rl*64;
    for (int i = 0; i < 64; ++i) acc += mrow[i] * ndw1[(16 + i)*64 + j];
    HD[idx] = fmaxf(acc, 0.f);
  }
  __syncthreads();
  if (t < 128) {
    int rl = t >> 4, o = t & 15;
    float acc = ndb2[o];
#pragma unroll
    for (int j = 0; j < 64; ++j) acc += HD[rl*64 + j] * ndw2[j*16 + o];
    out[(b*64 + r0 + rl)*16 + o] = fmaxf(acc, 0.f);
  }
}

extern "C" void kernel_launch(void* const* d_in, const int* in_sizes, int n_in,
                              void* d_out, int out_size, void* d_ws, size_t ws_size,
                              hipStream_t stream) {
  const float* ns   = (const float*)d_in[0];
  const float* et   = (const float*)d_in[1];
  const float* e0w1 = (const float*)d_in[2];
  const float* e0b1 = (const float*)d_in[3];
  const float* e0w2 = (const float*)d_in[4];
  const float* e0b2 = (const float*)d_in[5];
  const float* e1w1 = (const float*)d_in[6];
  const float* e1b1 = (const float*)d_in[7];
  const float* e1w2 = (const float*)d_in[8];
  const float* e1b2 = (const float*)d_in[9];
  const float* ndw1 = (const float*)d_in[10];
  const float* ndb1 = (const float*)d_in[11];
  const float* ndw2 = (const float*)d_in[12];
  const float* ndb2 = (const float*)d_in[13];

  float* P0 = (float*)d_ws;              // 4 x 524288 floats + 9216 ushort ~ 8.02 MB
  float* Q0 = P0 + 524288;
  float* P1 = Q0 + 524288;
  float* Q1 = P1 + 524288;
  unsigned short* W2TW = (unsigned short*)(Q1 + 524288);

  prep_kernel<<<2084, 256, 0, stream>>>(ns, e0w1, e0b1, e1w1, e1b1, e0w2, e1w2,
                                        P0, Q0, P1, Q1, W2TW);
  main_kernel<<<1024, 256, 0, stream>>>(ns, et, P0, Q0, P1, Q1, W2TW,
                                        e0b2, e1b2, ndw1, ndb1, ndw2, ndb2,
                                        (float*)d_out);
}